// Round 1
// baseline (445.116 us; speedup 1.0000x reference)
//
#include <hip/hip_runtime.h>
#include <math.h>

#define NB 4
#define NL 4096
#define NE 512
#define NH 8
#define ND 64
#define NF 2049      // NL/2 + 1
#define WSZ (NE * NE) // 262144 elements per weight matrix

static constexpr float INV_SQRT_N = 1.0f / 64.0f;   // 1/sqrt(4096), ortho norm

typedef __attribute__((ext_vector_type(8))) short bf16x8;
typedef __attribute__((ext_vector_type(4))) short short4v;
typedef __attribute__((ext_vector_type(4))) float f32x4;

__device__ __forceinline__ float2 cmul(float2 a, float2 b) {
    return make_float2(a.x * b.x - a.y * b.y, a.x * b.y + a.y * b.x);
}

__device__ __forceinline__ short cvt_bf16(float f) {
    unsigned u = __float_as_uint(f);
    unsigned r = (u + 0x7FFFu + ((u >> 16) & 1u)) >> 16;
    return (short)r;
}

__device__ __forceinline__ int pack_bf16x2(float a, float b) {
    return (int)(unsigned short)cvt_bf16(a) | ((int)(unsigned short)cvt_bf16(b) << 16);
}

__device__ __forceinline__ float2 unpk(int v) {
    return make_float2(__uint_as_float(((unsigned)v & 0xffffu) << 16),
                       __uint_as_float((unsigned)v & 0xffff0000u));
}

// base-4 digit reversal of a 12-bit index
__device__ __forceinline__ int b4rev(int t) {
    int r = __brev((unsigned)t) >> 20;
    return ((r & 0x555) << 1) | ((r & 0xAAA) >> 1);
}

// ---------------- one-time exact twiddles ----------------
__global__ __launch_bounds__(256) void twiddle_kernel(float2* __restrict__ twg) {
    int j = blockIdx.x * 256 + threadIdx.x;
    double ang = (2.0 * M_PI / (double)NL) * (double)j;
    double s, c;
    sincos(ang, &s, &c);
    twg[j] = make_float2((float)c, (float)s);
}

// ---------------- one-time weight cast fp32 -> bf16 (7 matrices) ----------------
__global__ __launch_bounds__(256) void castw_kernel(
    const float* __restrict__ w0, const float* __restrict__ w1,
    const float* __restrict__ w2, const float* __restrict__ w3,
    const float* __restrict__ w4, const float* __restrict__ w5,
    const float* __restrict__ w6, short* __restrict__ dst) {
    int which = blockIdx.y;
    const float* s = which == 0 ? w0 : which == 1 ? w1 : which == 2 ? w2 :
                     which == 3 ? w3 : which == 4 ? w4 : which == 5 ? w5 : w6;
    long i = (long)blockIdx.x * 1024 + threadIdx.x * 4;
    float4 v = *(const float4*)(s + i);
    short4v o = {cvt_bf16(v.x), cvt_bf16(v.y), cvt_bf16(v.z), cvt_bf16(v.w)};
    *(short4v*)(dst + (long)which * WSZ + i) = o;
}

// ---------------- LayerNorm: one row (512) per wave, bf16 output ----------------
__global__ __launch_bounds__(256) void ln_kernel(
    const float* __restrict__ x, const float* __restrict__ g,
    const float* __restrict__ be, short* __restrict__ xnb) {
    int wv = threadIdx.x >> 6, lane = threadIdx.x & 63;
    long row = (long)blockIdx.x * 4 + wv;
    const float* xp = x + row * NE + lane * 8;
    float4 a = *(const float4*)xp;
    float4 b = *(const float4*)(xp + 4);
    float s  = a.x + a.y + a.z + a.w + b.x + b.y + b.z + b.w;
    float ss = a.x * a.x + a.y * a.y + a.z * a.z + a.w * a.w
             + b.x * b.x + b.y * b.y + b.z * b.z + b.w * b.w;
#pragma unroll
    for (int o = 32; o; o >>= 1) { s += __shfl_xor(s, o); ss += __shfl_xor(ss, o); }
    float mu = s * (1.0f / NE);
    float var = ss * (1.0f / NE) - mu * mu;
    float rs = rsqrtf(var + 1e-5f);
    const float* gp = g + lane * 8;
    const float* bp = be + lane * 8;
    float4 g0 = *(const float4*)gp, g1 = *(const float4*)(gp + 4);
    float4 b0 = *(const float4*)bp, b1 = *(const float4*)(bp + 4);
    bf16x8 ov;
    ov[0] = cvt_bf16((a.x - mu) * rs * g0.x + b0.x);
    ov[1] = cvt_bf16((a.y - mu) * rs * g0.y + b0.y);
    ov[2] = cvt_bf16((a.z - mu) * rs * g0.z + b0.z);
    ov[3] = cvt_bf16((a.w - mu) * rs * g0.w + b0.w);
    ov[4] = cvt_bf16((b.x - mu) * rs * g1.x + b1.x);
    ov[5] = cvt_bf16((b.y - mu) * rs * g1.y + b1.y);
    ov[6] = cvt_bf16((b.z - mu) * rs * g1.z + b1.z);
    ov[7] = cvt_bf16((b.w - mu) * rs * g1.w + b1.w);
    *(bf16x8*)(xnb + row * NE + lane * 8) = ov;
}

// ---------------- radix-4 FFT stages in LDS (4096 pts, 6 stages) ----------------
template <int INV>
__device__ __forceinline__ void fft4_stages(float2* sdata, const float2* tws, int tid) {
#pragma unroll
    for (int st = 0; st < 6; ++st) {
        __syncthreads();
        int Q = 1 << (2 * st);
        int tq = 10 - 2 * st;
#pragma unroll
        for (int jj = 0; jj < 4; ++jj) {
            int j = tid + jj * 256;
            int k = j & (Q - 1);
            int i0 = ((j >> (2 * st)) << (2 * st + 2)) | k;
            float2 w1 = tws[k << tq];
            float2 w2 = tws[(2 * k) << tq];
            float2 w3 = cmul(w1, w2);
            float2 a = sdata[i0];
            float2 b = cmul(w1, sdata[i0 + Q]);
            float2 c = cmul(w2, sdata[i0 + 2 * Q]);
            float2 d = cmul(w3, sdata[i0 + 3 * Q]);
            float2 t0 = make_float2(a.x + c.x, a.y + c.y);
            float2 t1 = make_float2(a.x - c.x, a.y - c.y);
            float2 t2 = make_float2(b.x + d.x, b.y + d.y);
            float2 bd = make_float2(b.x - d.x, b.y - d.y);
            float2 t3 = INV ? make_float2(-bd.y, bd.x) : make_float2(bd.y, -bd.x);
            sdata[i0]         = make_float2(t0.x + t2.x, t0.y + t2.y);
            sdata[i0 + Q]     = make_float2(t1.x + t3.x, t1.y + t3.y);
            sdata[i0 + 2 * Q] = make_float2(t0.x - t2.x, t0.y - t2.y);
            sdata[i0 + 3 * Q] = make_float2(t1.x - t3.x, t1.y - t3.y);
        }
    }
    __syncthreads();
}

// XCD-aware e-pair swizzle: consecutive dispatch ids (round-robin over 8 XCDs)
// map to e-stripes 32 pairs apart, so each XCD owns a contiguous 64-column band.
__device__ __forceinline__ int ep_swizzle(int loc) {
    return ((loc & 7) << 5) | (loc >> 3);
}

// ---------------- forward rfft: 2 real bf16 columns in 1 complex FFT ----------------
__global__ __launch_bounds__(256) void rfft_pair(
    const short* __restrict__ xnb, const float2* __restrict__ twg,
    short* __restrict__ xr, short* __restrict__ xi) {
    __shared__ float2 sdata[NL];
    __shared__ float2 tws[NL / 2];
    int b = blockIdx.x >> 8;
    int e0 = ep_swizzle(blockIdx.x & 255) * 2;
    int tid = threadIdx.x;
    const short* xp = xnb + (long)b * NL * NE + e0;
#pragma unroll
    for (int jj = 0; jj < 16; ++jj) {
        int t = tid + jj * 256;
        int v = *(const int*)(xp + (long)t * NE);
        sdata[b4rev(t)] = unpk(v);
    }
#pragma unroll
    for (int jj = 0; jj < 8; ++jj) {
        int j = tid + jj * 256;
        float2 w = twg[j];
        tws[j] = make_float2(w.x, -w.y);   // forward: e^{-i theta}
    }
    fft4_stages<0>(sdata, tws, tid);
    short* xrp = xr + (long)b * NF * NE + e0;
    short* xip = xi + (long)b * NF * NE + e0;
    for (int f = tid; f < NF; f += 256) {
        int M = (NL - f) & (NL - 1);
        float2 zf = sdata[f], zm = sdata[M];
        float re0 = (zf.x + zm.x) * (0.5f * INV_SQRT_N);
        float im0 = (zf.y - zm.y) * (0.5f * INV_SQRT_N);
        float re1 = (zf.y + zm.y) * (0.5f * INV_SQRT_N);
        float im1 = (zm.x - zf.x) * (0.5f * INV_SQRT_N);
        *(int*)(xrp + (long)f * NE) = pack_bf16x2(re0, re1);
        *(int*)(xip + (long)f * NE) = pack_bf16x2(im0, im1);
    }
}

// ---------------- inverse rfft: bf16 in, bf16 out ----------------
__global__ __launch_bounds__(256) void irfft_pair(
    const short* __restrict__ orr, const short* __restrict__ oii,
    const float2* __restrict__ twg, short* __restrict__ yt) {
    __shared__ float2 sdata[NL];
    __shared__ float2 tws[NL / 2];
    int b = blockIdx.x >> 8;
    int e0 = ep_swizzle(blockIdx.x & 255) * 2;
    int tid = threadIdx.x;
    const short* orp = orr + (long)b * NF * NE + e0;
    const short* oip = oii + (long)b * NF * NE + e0;
    for (int f = tid; f < NF; f += 256) {
        float2 vr = unpk(*(const int*)(orp + (long)f * NE));  // (O0r, O1r)
        float2 vi = unpk(*(const int*)(oip + (long)f * NE));  // (O0i, O1i)
        if (f == 0 || f == NL / 2) vi = make_float2(0.f, 0.f);  // C2R ignores these
        sdata[b4rev(f)] = make_float2(vr.x - vi.y, vi.x + vr.y);
        if (f > 0 && f < NL / 2) {
            sdata[b4rev(NL - f)] = make_float2(vr.x + vi.y, vr.y - vi.x);
        }
    }
#pragma unroll
    for (int jj = 0; jj < 8; ++jj) {
        int j = tid + jj * 256;
        tws[j] = twg[j];                   // inverse: e^{+i theta}
    }
    fft4_stages<1>(sdata, tws, tid);
    short* yp = yt + (long)b * NL * NE + e0;
#pragma unroll
    for (int jj = 0; jj < 16; ++jj) {
        int t = tid + jj * 256;
        float2 z = sdata[t];
        *(int*)(yp + (long)t * NE) = pack_bf16x2(z.x * INV_SQRT_N, z.y * INV_SQRT_N);
    }
}

// ---------------- bf16 MFMA GEMM core ----------------
__device__ __forceinline__ void gemm_core(
    const short* __restrict__ A, const short* __restrict__ W,
    const float* __restrict__ bias, float scale, short* __restrict__ Cb,
    float* __restrict__ Cf, int N) {
    __shared__ short As[128][40];
    __shared__ short Bs[128][40];
    int o0 = blockIdx.x * 128;
    int n0 = blockIdx.y * 128;
    int tid = threadIdx.x;
    int lane = tid & 63, wv = tid >> 6;
    int quad = lane >> 4, cl = lane & 15;
    int rbase = (wv >> 1) << 6;
    int cbase = (wv & 1) << 6;
    int srow = tid >> 2;    // 0..63
    int sseg = tid & 3;     // 0..3
    f32x4 acc[4][4];
#pragma unroll
    for (int i = 0; i < 4; ++i)
#pragma unroll
        for (int j = 0; j < 4; ++j) acc[i][j] = (f32x4){0, 0, 0, 0};

    int ra = n0 + srow;      if (ra >= N) ra = N - 1;
    int rb = n0 + srow + 64; if (rb >= N) rb = N - 1;
    const short* Ap0 = A + (long)ra * NE + sseg * 8;
    const short* Ap1 = A + (long)rb * NE + sseg * 8;
    const short* Wp0 = W + (long)(o0 + srow) * NE + sseg * 8;
    const short* Wp1 = W + (long)(o0 + srow + 64) * NE + sseg * 8;

    bf16x8 a0 = *(const bf16x8*)Ap0, a1 = *(const bf16x8*)Ap1;
    bf16x8 b0 = *(const bf16x8*)Wp0, b1 = *(const bf16x8*)Wp1;

    for (int kt = 0; kt < 16; ++kt) {
        __syncthreads();
        *(bf16x8*)&As[srow][sseg * 8] = a0;
        *(bf16x8*)&As[srow + 64][sseg * 8] = a1;
        *(bf16x8*)&Bs[srow][sseg * 8] = b0;
        *(bf16x8*)&Bs[srow + 64][sseg * 8] = b1;
        __syncthreads();
        if (kt < 15) {
            int ko = (kt + 1) * 32;
            a0 = *(const bf16x8*)(Ap0 + ko);
            a1 = *(const bf16x8*)(Ap1 + ko);
            b0 = *(const bf16x8*)(Wp0 + ko);
            b1 = *(const bf16x8*)(Wp1 + ko);
        }
        bf16x8 ar[4], br[4];
#pragma unroll
        for (int i = 0; i < 4; ++i) ar[i] = *(const bf16x8*)&As[rbase + 16 * i + cl][quad * 8];
#pragma unroll
        for (int j = 0; j < 4; ++j) br[j] = *(const bf16x8*)&Bs[cbase + 16 * j + cl][quad * 8];
#pragma unroll
        for (int i = 0; i < 4; ++i)
#pragma unroll
            for (int j = 0; j < 4; ++j)
                acc[i][j] = __builtin_amdgcn_mfma_f32_16x16x32_bf16(ar[i], br[j], acc[i][j], 0, 0, 0);
    }
    float bv[4];
#pragma unroll
    for (int j = 0; j < 4; ++j) bv[j] = bias ? bias[o0 + cbase + 16 * j + cl] : 0.0f;
#pragma unroll
    for (int i = 0; i < 4; ++i) {
#pragma unroll
        for (int r = 0; r < 4; ++r) {
            int n = n0 + rbase + 16 * i + quad * 4 + r;
            if (n >= N) continue;
#pragma unroll
            for (int j = 0; j < 4; ++j) {
                float v = (acc[i][j][r] + bv[j]) * scale;
                int o = o0 + cbase + 16 * j + cl;
                if (Cb) Cb[(long)n * NE + o] = cvt_bf16(v);
                else    Cf[(long)n * NE + o] = v;
            }
        }
    }
}

__global__ __launch_bounds__(256) void gemm_qkv(
    const short* __restrict__ A,
    const short* __restrict__ W0, const short* __restrict__ W1, const short* __restrict__ W2,
    const float* __restrict__ b0, const float* __restrict__ b1, const float* __restrict__ b2,
    short* __restrict__ C0, short* __restrict__ C1, short* __restrict__ C2, int N) {
    int z = blockIdx.z;
    const short* W = z == 0 ? W0 : z == 1 ? W1 : W2;
    const float* bb = z == 0 ? b0 : z == 1 ? b1 : b2;
    short* C = z == 0 ? C0 : z == 1 ? C1 : C2;
    gemm_core(A, W, bb, z == 0 ? 0.125f : 1.0f, C, nullptr, N);
}

__global__ __launch_bounds__(256) void gemm_out(
    const short* __restrict__ A, const short* __restrict__ W,
    float* __restrict__ C, int N) {
    gemm_core(A, W, nullptr, 1.0f, nullptr, C, N);
}

// ---------------- MFMA flash attention: register-resident P (S^T trick) ----------------
// S^T = K.Q^T via mfma_16x16x32 (C rows = key, cols = q). Its C-layout IS the
// B-operand layout of mfma_16x16x16bf16_1k, so P never touches LDS:
// O^T = V^T.P^T accumulated per 16-d tile. l is per-lane (q=lane&15).
// Vt swizzled at 4-short granularity: col-group g' = g ^ ((d>>2)&15).
__global__ __launch_bounds__(256) void fattn_mfma(
    const short* __restrict__ Qr, const short* __restrict__ Qi,
    const short* __restrict__ Kr, const short* __restrict__ Ki,
    const short* __restrict__ Vr, const short* __restrict__ Vi,
    short* __restrict__ Orb, short* __restrict__ Oib) {
    __shared__ short Ks[2][64][72];   // [r/i][key][d]
    __shared__ short Vt[2][64][72];   // [r/i][d][key 4-swizzled]
    int tid = threadIdx.x;
    int wv = tid >> 6, lane = tid & 63;
    int quad = lane >> 4, cl = lane & 15;
    int h = blockIdx.y, b = blockIdx.z;
    long base = (long)b * NF * NE + h * ND;
    int qbase = blockIdx.x * 64 + wv * 16;

    int sk0 = (tid >> 4) << 2;   // staged keys (group g0 = tid>>4)
    int sd0 = (tid & 15) << 2;   // staged dims
    int g0 = tid >> 4;
    int dsw = tid & 15;          // (d>>2) for all 4 staged dim rows

    // ---- Q fragments: B-operand of S^T (B[k=d][n=q]), pre-scaled by 1/8 ----
    bf16x8 qar[2], qai[2];
    {
        int qrow = qbase + cl; if (qrow >= NF) qrow = NF - 1;
        const short* pr = Qr + base + (long)qrow * NE + 8 * quad;
        const short* pi = Qi + base + (long)qrow * NE + 8 * quad;
        qar[0] = *(const bf16x8*)pr;
        qar[1] = *(const bf16x8*)(pr + 32);
        qai[0] = *(const bf16x8*)pi;
        qai[1] = *(const bf16x8*)(pi + 32);
    }

    float ls = 0.f;
    f32x4 Or2[4], Oi2[4];   // O^T tiles: [nt], rows d=16nt+quad*4+r, col q=cl
#pragma unroll
    for (int t = 0; t < 4; ++t) { Or2[t] = (f32x4){0,0,0,0}; Oi2[t] = (f32x4){0,0,0,0}; }

    short4v lk0[4], lk1[4], lv0[4], lv1[4];
    auto ldtile = [&](int m0) {
        short4v z4 = {0, 0, 0, 0};
#pragma unroll
        for (int kk = 0; kk < 4; ++kk) {
            int mg = m0 + sk0 + kk;
            if (mg < NF) {
                long roff = base + (long)mg * NE + sd0;
                lk0[kk] = *(const short4v*)(Kr + roff);
                lk1[kk] = *(const short4v*)(Ki + roff);
                lv0[kk] = *(const short4v*)(Vr + roff);
                lv1[kk] = *(const short4v*)(Vi + roff);
            } else { lk0[kk] = z4; lk1[kk] = z4; lv0[kk] = z4; lv1[kk] = z4; }
        }
    };
    ldtile(0);

    for (int kt = 0; kt < 33; ++kt) {
        int m0 = kt * 64;
        __syncthreads();
        // ---- stage K (row-major) + V (transposed, 4-granular XOR swizzle) ----
#pragma unroll
        for (int kk = 0; kk < 4; ++kk) {
            *(short4v*)&Ks[0][sk0 + kk][sd0] = lk0[kk];
            *(short4v*)&Ks[1][sk0 + kk][sd0] = lk1[kk];
        }
        {
            int cv = (g0 ^ dsw) << 2;
#pragma unroll
            for (int dd = 0; dd < 4; ++dd) {
                short4v t0 = {lv0[0][dd], lv0[1][dd], lv0[2][dd], lv0[3][dd]};
                *(short4v*)&Vt[0][sd0 + dd][cv] = t0;
                short4v t1 = {lv1[0][dd], lv1[1][dd], lv1[2][dd], lv1[3][dd]};
                *(short4v*)&Vt[1][sd0 + dd][cv] = t1;
            }
        }
        __syncthreads();
        if (kt + 1 < 33) ldtile(m0 + 64);   // prefetch next tile into regs

        // ---- S^T = K.Q^T (16 MFMAs): c[t] rows = key quad*4+r, col = q ----
        f32x4 c[4];
#pragma unroll
        for (int t = 0; t < 4; ++t) {
            f32x4 acc = (f32x4){0, 0, 0, 0};
            const short* kr = &Ks[0][cl + 16 * t][8 * quad];
            const short* ki = &Ks[1][cl + 16 * t][8 * quad];
            acc = __builtin_amdgcn_mfma_f32_16x16x32_bf16(*(const bf16x8*)kr, qar[0], acc, 0, 0, 0);
            acc = __builtin_amdgcn_mfma_f32_16x16x32_bf16(*(const bf16x8*)(kr + 32), qar[1], acc, 0, 0, 0);
            acc = __builtin_amdgcn_mfma_f32_16x16x32_bf16(*(const bf16x8*)ki, qai[0], acc, 0, 0, 0);
            acc = __builtin_amdgcn_mfma_f32_16x16x32_bf16(*(const bf16x8*)(ki + 32), qai[1], acc, 0, 0, 0);
            c[t] = acc;
        }

        // ---- exp (no max-sub: |s|<~5), mask, per-lane l, pack B-operands ----
        short4v pb[4];
#pragma unroll
        for (int t = 0; t < 4; ++t) {
            int kbase = m0 + 16 * t + quad * 4;
#pragma unroll
            for (int r = 0; r < 4; ++r) {
                float p = (kbase + r < NF) ? __expf(c[t][r]) : 0.0f;
                c[t][r] = p;
                ls += p;
            }
            pb[t] = (short4v){cvt_bf16(c[t][0]), cvt_bf16(c[t][1]),
                              cvt_bf16(c[t][2]), cvt_bf16(c[t][3])};
        }

        // ---- O^T += V^T.P^T  (32 mfma_16x16x16, P in registers) ----
#pragma unroll
        for (int nt = 0; nt < 4; ++nt) {
            int d = cl + 16 * nt;
            int dg = (d >> 2) & 15;
#pragma unroll
            for (int t = 0; t < 4; ++t) {
                int g = 4 * t + quad;
                int cv = ((g ^ dg) << 2);
                short4v va = *(const short4v*)&Vt[0][d][cv];
                short4v vb = *(const short4v*)&Vt[1][d][cv];
                Or2[nt] = __builtin_amdgcn_mfma_f32_16x16x16bf16_1k(va, pb[t], Or2[nt], 0, 0, 0);
                Oi2[nt] = __builtin_amdgcn_mfma_f32_16x16x16bf16_1k(vb, pb[t], Oi2[nt], 0, 0, 0);
            }
        }
    }

    // ---- l reduce over quads (all m-chunks), then write O as bf16 ----
    ls += __shfl_xor(ls, 16);
    ls += __shfl_xor(ls, 32);
    float inv = 1.0f / ls;
    int q = qbase + cl;
    if (q < NF) {
        short* po = Orb + base + (long)q * NE;
        short* pi2 = Oib + base + (long)q * NE;
#pragma unroll
        for (int nt = 0; nt < 4; ++nt) {
            int d0 = 16 * nt + quad * 4;
            short4v so = {cvt_bf16(Or2[nt][0] * inv), cvt_bf16(Or2[nt][1] * inv),
                          cvt_bf16(Or2[nt][2] * inv), cvt_bf16(Or2[nt][3] * inv)};
            *(short4v*)(po + d0) = so;
            short4v si = {cvt_bf16(Oi2[nt][0] * inv), cvt_bf16(Oi2[nt][1] * inv),
                          cvt_bf16(Oi2[nt][2] * inv), cvt_bf16(Oi2[nt][3] * inv)};
            *(short4v*)(pi2 + d0) = si;
        }
    }
}

extern "C" void kernel_launch(void* const* d_in, const int* in_sizes, int n_in,
                              void* d_out, int out_size, void* d_ws, size_t ws_size,
                              hipStream_t stream) {
    const float* x   = (const float*)d_in[0];
    const float* g   = (const float*)d_in[1];
    const float* be  = (const float*)d_in[2];
    const float* Wqr = (const float*)d_in[3];
    const float* bqr = (const float*)d_in[4];
    const float* Wqi = (const float*)d_in[5];
    const float* bqi = (const float*)d_in[6];
    const float* Wkr = (const float*)d_in[7];
    const float* bkr = (const float*)d_in[8];
    const float* Wki = (const float*)d_in[9];
    const float* bki = (const float*)d_in[10];
    const float* Wvr = (const float*)d_in[11];
    const float* bvr = (const float*)d_in[12];
    const float* Wvi = (const float*)d_in[13];
    const float* bvi = (const float*)d_in[14];
    const float* Wo  = (const float*)d_in[15];
    float* out = (float*)d_out;

    const long SZ_T = (long)NB * NL * NE;  // 8,388,608
    const long SZ_F = (long)NB * NF * NE;  // 4,196,352
    float2* twg = (float2*)d_ws;            // 2048 float2
    short* xnb = (short*)(twg + 2048);      // bf16 region
    short* xr  = xnb + SZ_T;
    short* xi  = xr + SZ_F;
    short* Qr  = xi + SZ_F;
    short* Qi  = Qr + SZ_F;
    short* Kr  = Qi + SZ_F;
    short* Ki  = Kr + SZ_F;
    short* Vr  = Ki + SZ_F;
    short* Vi  = Vr + SZ_F;
    short* Orb = Vi + SZ_F;
    short* Oib = Orb + SZ_F;
    short* yt  = Oib + SZ_F;                // SZ_T bf16
    short* wb  = yt + SZ_T;                 // 7 * WSZ bf16

    twiddle_kernel<<<NL / 2 / 256, 256, 0, stream>>>(twg);
    castw_kernel<<<dim3(WSZ / 1024, 7), 256, 0, stream>>>(Wqr, Wqi, Wkr, Wki, Wvr, Wvi, Wo, wb);
    ln_kernel<<<NB * NL / 4, 256, 0, stream>>>(x, g, be, xnb);
    rfft_pair<<<NB * 256, 256, 0, stream>>>(xnb, twg, xr, xi);
    int Nf = NB * NF;                       // 8196
    dim3 gq(NE / 128, (Nf + 127) / 128, 3);
    gemm_qkv<<<gq, 256, 0, stream>>>(xr, wb + 0L * WSZ, wb + 2L * WSZ, wb + 4L * WSZ,
                                     bqr, bkr, bvr, Qr, Kr, Vr, Nf);
    gemm_qkv<<<gq, 256, 0, stream>>>(xi, wb + 1L * WSZ, wb + 3L * WSZ, wb + 5L * WSZ,
                                     bqi, bki, bvi, Qi, Ki, Vi, Nf);
    fattn_mfma<<<dim3(33, NH, NB), 256, 0, stream>>>(Qr, Qi, Kr, Ki, Vr, Vi, Orb, Oib);
    irfft_pair<<<NB * 256, 256, 0, stream>>>(Orb, Oib, twg, yt);
    gemm_out<<<dim3(NE / 128, NB * NL / 128), 256, 0, stream>>>(yt, wb + 6L * WSZ, out, NB * NL);
}